// Round 3
// baseline (271.009 us; speedup 1.0000x reference)
//
#include <hip/hip_runtime.h>

// VQ-VAE codebook quantization forward — bit-replicates numpy fp32 semantics
// (np pairwise sumsq, sequential-FMA dot, fl(fl(cb+xs) - fl(2dot)), first-min
// argmin). PASSED round 2 with absmax 0.
//
// Perf round: VGPR_Count=44 proved the compiler re-loaded x[64] from global
// inside the k-loop (targeting 8 waves/EU). Fix:
//  - __launch_bounds__(256, 2): VGPR budget 256 -> x stays resident.
//  - codebook staged in LDS in two 64 KB halves (2 blocks/CU preserved);
//    uniform-address reads = broadcast, no bank conflicts, no vmcnt in loop.

#define KCODES 512
#define KHALF 256
#define DDIM 64
#define HWSZ 4096            // H*W
#define NPOS 131072          // B*H*W
#define OUT2_OFF 8388608     // B*D*H*W

// numpy pairwise_sum (n=64 branch) of rounded squares, fp32, no fma.
__device__ __forceinline__ float np_sumsq64(const float* __restrict__ a) {
#pragma clang fp contract(off)
    float r0 = a[0] * a[0], r1 = a[1] * a[1], r2 = a[2] * a[2], r3 = a[3] * a[3];
    float r4 = a[4] * a[4], r5 = a[5] * a[5], r6 = a[6] * a[6], r7 = a[7] * a[7];
#pragma unroll
    for (int i = 8; i < 64; i += 8) {
        r0 += a[i + 0] * a[i + 0];
        r1 += a[i + 1] * a[i + 1];
        r2 += a[i + 2] * a[i + 2];
        r3 += a[i + 3] * a[i + 3];
        r4 += a[i + 4] * a[i + 4];
        r5 += a[i + 5] * a[i + 5];
        r6 += a[i + 6] * a[i + 6];
        r7 += a[i + 7] * a[i + 7];
    }
    return ((r0 + r1) + (r2 + r3)) + ((r4 + r5) + (r6 + r7));
}

__global__ __launch_bounds__(256, 2) void vq_fp32exact_argmin(
    const float* __restrict__ z, const float* __restrict__ cb,
    float* __restrict__ out)
{
#pragma clang fp contract(off)
    __shared__ float s_cb[KHALF * DDIM];      // 64 KB: half the codebook
    __shared__ float s_cbsqr[KCODES];         // 2 KB
    const int tid = threadIdx.x;

    for (int k = tid; k < KCODES; k += 256)
        s_cbsqr[k] = np_sumsq64(cb + k * DDIM);

    const int n = blockIdx.x * 256 + tid;      // grid = NPOS/256
    const int b = n >> 12;
    const int hw = n & 4095;
    const long base = (long)b * (DDIM * HWSZ) + hw;

    // Gather x (NCHW): lanes differ only in hw -> coalesced per d.
    float x[DDIM];
#pragma unroll
    for (int d = 0; d < DDIM; ++d) x[d] = z[base + (long)d * HWSZ];

    const float xsqr = np_sumsq64(x);

    float best = 3.4e38f;
    int idx = 0;

    for (int half = 0; half < 2; ++half) {
        __syncthreads();                       // protect s_cb reuse
        // Stage 64 KB codebook half: fp32 bit-copy, coalesced float4.
        const float4* src = (const float4*)(cb + half * (KHALF * DDIM));
        float4* dst = (float4*)s_cb;
        for (int i = tid; i < KHALF * DDIM / 4; i += 256) dst[i] = src[i];
        __syncthreads();

        const int kbase = half * KHALF;
        for (int k = 0; k < KHALF; k += 4) {   // 4 codes in flight (ILP)
            const float* c = s_cb + k * DDIM;  // uniform addr -> broadcast
            float d0 = 0.f, d1 = 0.f, d2 = 0.f, d3 = 0.f;
#pragma unroll
            for (int d = 0; d < DDIM; ++d) {
                d0 = fmaf(x[d], c[d], d0);
                d1 = fmaf(x[d], c[d + DDIM], d1);
                d2 = fmaf(x[d], c[d + 2 * DDIM], d2);
                d3 = fmaf(x[d], c[d + 3 * DDIM], d3);
            }
            const int kk = kbase + k;
            float t0 = s_cbsqr[kk]     + xsqr;  float e0 = t0 - 2.0f * d0;
            float t1 = s_cbsqr[kk + 1] + xsqr;  float e1 = t1 - 2.0f * d1;
            float t2 = s_cbsqr[kk + 2] + xsqr;  float e2 = t2 - 2.0f * d2;
            float t3 = s_cbsqr[kk + 3] + xsqr;  float e3 = t3 - 2.0f * d3;
            if (e0 < best) { best = e0; idx = kk; }
            if (e1 < best) { best = e1; idx = kk + 1; }
            if (e2 < best) { best = e2; idx = kk + 2; }
            if (e3 < best) { best = e3; idx = kk + 3; }
        }
    }

    // Scatter selected code to both outputs (NCHW).
    const float4* crow = (const float4*)(cb + idx * DDIM);
    float* o0 = out + base;
    float* o1 = o0 + OUT2_OFF;
#pragma unroll
    for (int q = 0; q < DDIM / 4; ++q) {
        float4 v = crow[q];
        const long d0 = (long)(q * 4) * HWSZ;
        o0[d0]            = v.x; o0[d0 + HWSZ]     = v.y;
        o0[d0 + 2 * HWSZ] = v.z; o0[d0 + 3 * HWSZ] = v.w;
        o1[d0]            = v.x; o1[d0 + HWSZ]     = v.y;
        o1[d0 + 2 * HWSZ] = v.z; o1[d0 + 3 * HWSZ] = v.w;
    }
}

extern "C" void kernel_launch(void* const* d_in, const int* in_sizes, int n_in,
                              void* d_out, int out_size, void* d_ws, size_t ws_size,
                              hipStream_t stream) {
    const float* z  = (const float*)d_in[0];   // [32,64,64,64] fp32
    const float* cb = (const float*)d_in[1];   // [512,64] fp32
    float* out = (float*)d_out;                // 2 * 8388608 fp32
    vq_fp32exact_argmin<<<NPOS / 256, 256, 0, stream>>>(z, cb, out);
}

// Round 4
// 244.246 us; speedup vs baseline: 1.1096x; 1.1096x over previous
//
#include <hip/hip_runtime.h>

// VQ-VAE codebook quantization forward — bit-replicates numpy fp32 semantics
// (np pairwise sumsq, sequential-FMA dot, fl(fl(cb+xs) - fl(2dot)), first-min
// argmin). PASSED rounds 2/3 with absmax 0.
//
// R3 lesson: LDS broadcast streaming of the codebook is LDS-pipe-bound
// (~12 cyc/b128, per-CU shared => ~300us of pipe time). This round:
//  - codebook read from global with wave-uniform addresses (readfirstlane
//    base) -> SMEM/L1 path, no LDS in the hot loop.
//  - K split across the 4 waves of a block (wave w -> codes [128w,128w+128)),
//    64 positions/block -> 2048 blocks = 32 waves/CU supplied (was 8).
//    Merge preserves np.argmin first-min order (ascending k).

#define KCODES 512
#define KQ 128               // codes per wave
#define DDIM 64
#define HWSZ 4096            // H*W
#define NPOS 131072          // B*H*W
#define POSB 64              // positions per block
#define OUT2_OFF 8388608     // B*D*H*W

// numpy pairwise_sum (n=64 branch) of rounded squares, fp32, no fma.
__device__ __forceinline__ float np_sumsq64(const float* __restrict__ a) {
#pragma clang fp contract(off)
    float r0 = a[0] * a[0], r1 = a[1] * a[1], r2 = a[2] * a[2], r3 = a[3] * a[3];
    float r4 = a[4] * a[4], r5 = a[5] * a[5], r6 = a[6] * a[6], r7 = a[7] * a[7];
#pragma unroll
    for (int i = 8; i < 64; i += 8) {
        r0 += a[i + 0] * a[i + 0];
        r1 += a[i + 1] * a[i + 1];
        r2 += a[i + 2] * a[i + 2];
        r3 += a[i + 3] * a[i + 3];
        r4 += a[i + 4] * a[i + 4];
        r5 += a[i + 5] * a[i + 5];
        r6 += a[i + 6] * a[i + 6];
        r7 += a[i + 7] * a[i + 7];
    }
    return ((r0 + r1) + (r2 + r3)) + ((r4 + r5) + (r6 + r7));
}

__global__ __launch_bounds__(256, 4) void vq_np_argmin_ksplit(
    const float* __restrict__ z, const float* __restrict__ cb,
    float* __restrict__ out)
{
#pragma clang fp contract(off)
    __shared__ float s_cbsqr[KCODES];      // 2 KB
    __shared__ float s_best[4 * POSB];     // 1 KB
    __shared__ int   s_bidx[4 * POSB];     // 1 KB

    const int tid = threadIdx.x;
    const int wave = tid >> 6;
    const int lane = tid & 63;

    // np-exact ||c_k||^2, cooperatively, once per block.
    for (int k = tid; k < KCODES; k += 256)
        s_cbsqr[k] = np_sumsq64(cb + k * DDIM);

    // This block's 64 positions; lane -> position (coalesced everywhere).
    const int n = blockIdx.x * POSB + lane;
    const int b = n >> 12;
    const int hw = n & 4095;
    const long base = (long)b * (DDIM * HWSZ) + hw;

    float x[DDIM];
#pragma unroll
    for (int d = 0; d < DDIM; ++d) x[d] = z[base + (long)d * HWSZ];

    const float xsqr = np_sumsq64(x);
    __syncthreads();   // s_cbsqr ready

    // Wave-uniform k-base (readfirstlane -> SGPR => uniform/scalar loads).
    const int kq = __builtin_amdgcn_readfirstlane(wave * KQ);

    float best = 3.4e38f;
    int idx = kq;
    for (int kk = 0; kk < KQ; kk += 4) {       // 4 codes in flight (ILP)
        const float* c = cb + (kq + kk) * DDIM;  // wave-uniform address
        float d0 = 0.f, d1 = 0.f, d2 = 0.f, d3 = 0.f;
#pragma unroll
        for (int d = 0; d < DDIM; ++d) {
            d0 = fmaf(x[d], c[d], d0);
            d1 = fmaf(x[d], c[d + DDIM], d1);
            d2 = fmaf(x[d], c[d + 2 * DDIM], d2);
            d3 = fmaf(x[d], c[d + 3 * DDIM], d3);
        }
        const int kk0 = kq + kk;
        float t0 = s_cbsqr[kk0]     + xsqr;  float e0 = t0 - 2.0f * d0;
        float t1 = s_cbsqr[kk0 + 1] + xsqr;  float e1 = t1 - 2.0f * d1;
        float t2 = s_cbsqr[kk0 + 2] + xsqr;  float e2 = t2 - 2.0f * d2;
        float t3 = s_cbsqr[kk0 + 3] + xsqr;  float e3 = t3 - 2.0f * d3;
        if (e0 < best) { best = e0; idx = kk0; }
        if (e1 < best) { best = e1; idx = kk0 + 1; }
        if (e2 < best) { best = e2; idx = kk0 + 2; }
        if (e3 < best) { best = e3; idx = kk0 + 3; }
    }

    s_best[wave * POSB + lane] = best;
    s_bidx[wave * POSB + lane] = idx;
    __syncthreads();

    // Merge 4 quarters in ascending-wave (= ascending-k) order, strict '<'
    // => identical to np.argmin first-min over all 512 codes.
    float gb = s_best[lane];
    int gi = s_bidx[lane];
#pragma unroll
    for (int w = 1; w < 4; ++w) {
        float bw = s_best[w * POSB + lane];
        int   iw = s_bidx[w * POSB + lane];
        if (bw < gb) { gb = bw; gi = iw; }
    }

    // Scatter: wave w writes d-range [16w, 16w+16) for all 64 positions.
    const float4* crow = (const float4*)(cb + gi * DDIM);
    float* o0 = out + base;
    float* o1 = o0 + OUT2_OFF;
#pragma unroll
    for (int q = 0; q < 4; ++q) {
        float4 v = crow[wave * 4 + q];
        const long db = (long)(wave * 16 + q * 4) * HWSZ;
        o0[db]            = v.x; o0[db + HWSZ]     = v.y;
        o0[db + 2 * HWSZ] = v.z; o0[db + 3 * HWSZ] = v.w;
        o1[db]            = v.x; o1[db + HWSZ]     = v.y;
        o1[db + 2 * HWSZ] = v.z; o1[db + 3 * HWSZ] = v.w;
    }
}

extern "C" void kernel_launch(void* const* d_in, const int* in_sizes, int n_in,
                              void* d_out, int out_size, void* d_ws, size_t ws_size,
                              hipStream_t stream) {
    const float* z  = (const float*)d_in[0];   // [32,64,64,64] fp32
    const float* cb = (const float*)d_in[1];   // [512,64] fp32
    float* out = (float*)d_out;                // 2 * 8388608 fp32
    vq_np_argmin_ksplit<<<NPOS / POSB, 256, 0, stream>>>(z, cb, out);
}

// Round 5
// 240.703 us; speedup vs baseline: 1.1259x; 1.0147x over previous
//
#include <hip/hip_runtime.h>

// VQ-VAE codebook quantization forward — bit-replicates numpy fp32 semantics
// (np pairwise sumsq, sequential-FMA dot, fl(fl(cb+xs) - fl(2dot)), first-min
// argmin over ascending k). PASSED rounds 2-4 with absmax 0.
//
// R4 lesson: even with __launch_bounds__(256,4) the compiler rematerializes
// x[64] from global inside the k-loop (VGPR_Count=44 both rounds). This round
// pins x into VGPRs with an empty asm barrier ("+v" constraint) so remat is
// impossible; codebook stays on the SMEM path (readfirstlane-uniform base).

#define KCODES 512
#define KQ 128               // codes per wave (K split across 4 waves)
#define DDIM 64
#define HWSZ 4096            // H*W
#define NPOS 131072          // B*H*W
#define POSB 64              // positions per block
#define OUT2_OFF 8388608     // B*D*H*W

// numpy pairwise_sum (n=64 branch) of rounded squares, fp32, no fma.
__device__ __forceinline__ float np_sumsq64(const float* __restrict__ a) {
#pragma clang fp contract(off)
    float r0 = a[0] * a[0], r1 = a[1] * a[1], r2 = a[2] * a[2], r3 = a[3] * a[3];
    float r4 = a[4] * a[4], r5 = a[5] * a[5], r6 = a[6] * a[6], r7 = a[7] * a[7];
#pragma unroll
    for (int i = 8; i < 64; i += 8) {
        r0 += a[i + 0] * a[i + 0];
        r1 += a[i + 1] * a[i + 1];
        r2 += a[i + 2] * a[i + 2];
        r3 += a[i + 3] * a[i + 3];
        r4 += a[i + 4] * a[i + 4];
        r5 += a[i + 5] * a[i + 5];
        r6 += a[i + 6] * a[i + 6];
        r7 += a[i + 7] * a[i + 7];
    }
    return ((r0 + r1) + (r2 + r3)) + ((r4 + r5) + (r6 + r7));
}

__global__ __launch_bounds__(256, 4) void vq_np_argmin_pinned(
    const float* __restrict__ z, const float* __restrict__ cb,
    float* __restrict__ out)
{
#pragma clang fp contract(off)
    __shared__ float s_cbsqr[KCODES];      // 2 KB
    __shared__ float s_best[4 * POSB];     // 1 KB
    __shared__ int   s_bidx[4 * POSB];     // 1 KB

    const int tid = threadIdx.x;
    const int wave = tid >> 6;
    const int lane = tid & 63;

    // np-exact ||c_k||^2, cooperatively, once per block.
    for (int k = tid; k < KCODES; k += 256)
        s_cbsqr[k] = np_sumsq64(cb + k * DDIM);

    // lane -> position (coalesced global access in every phase).
    const int n = blockIdx.x * POSB + lane;
    const int b = n >> 12;
    const int hw = n & 4095;
    const long base = (long)b * (DDIM * HWSZ) + hw;

    float x[DDIM];
#pragma unroll
    for (int d = 0; d < DDIM; ++d) x[d] = z[base + (long)d * HWSZ];
    // Pin x into VGPRs: opaque to the compiler -> cannot rematerialize by
    // re-loading from global inside the k-loop (R3/R4: VGPR_Count=44 remat).
#pragma unroll
    for (int d = 0; d < DDIM; ++d) asm volatile("" : "+v"(x[d]));

    const float xsqr = np_sumsq64(x);
    __syncthreads();   // s_cbsqr ready

    // Wave-uniform k-base -> SGPR -> codebook rows go through s_load (SMEM).
    const int kq = __builtin_amdgcn_readfirstlane(wave * KQ);

    float best = 3.4e38f;
    int idx = kq;
    for (int kk = 0; kk < KQ; kk += 4) {         // 4 codes in flight (ILP)
        const float* c = cb + (kq + kk) * DDIM;  // wave-uniform address
        float d0 = 0.f, d1 = 0.f, d2 = 0.f, d3 = 0.f;
#pragma unroll
        for (int d = 0; d < DDIM; ++d) {
            d0 = fmaf(x[d], c[d], d0);
            d1 = fmaf(x[d], c[d + DDIM], d1);
            d2 = fmaf(x[d], c[d + 2 * DDIM], d2);
            d3 = fmaf(x[d], c[d + 3 * DDIM], d3);
        }
        const int kk0 = kq + kk;
        // fl(t - 2d) == fma(-2,d,t) since 2d is exact; single rounding.
        float t0 = s_cbsqr[kk0]     + xsqr;  float e0 = fmaf(-2.0f, d0, t0);
        float t1 = s_cbsqr[kk0 + 1] + xsqr;  float e1 = fmaf(-2.0f, d1, t1);
        float t2 = s_cbsqr[kk0 + 2] + xsqr;  float e2 = fmaf(-2.0f, d2, t2);
        float t3 = s_cbsqr[kk0 + 3] + xsqr;  float e3 = fmaf(-2.0f, d3, t3);
        if (e0 < best) { best = e0; idx = kk0; }
        if (e1 < best) { best = e1; idx = kk0 + 1; }
        if (e2 < best) { best = e2; idx = kk0 + 2; }
        if (e3 < best) { best = e3; idx = kk0 + 3; }
    }

    s_best[wave * POSB + lane] = best;
    s_bidx[wave * POSB + lane] = idx;
    __syncthreads();

    // Merge 4 quarters in ascending-wave (= ascending-k) order, strict '<'
    // => identical to np.argmin first-min over all 512 codes.
    float gb = s_best[lane];
    int gi = s_bidx[lane];
#pragma unroll
    for (int w = 1; w < 4; ++w) {
        float bw = s_best[w * POSB + lane];
        int   iw = s_bidx[w * POSB + lane];
        if (bw < gb) { gb = bw; gi = iw; }
    }

    // Scatter: wave w writes d-range [16w, 16w+16) for all 64 positions.
    const float4* crow = (const float4*)(cb + gi * DDIM);
    float* o0 = out + base;
    float* o1 = o0 + OUT2_OFF;
#pragma unroll
    for (int q = 0; q < 4; ++q) {
        float4 v = crow[wave * 4 + q];
        const long db = (long)(wave * 16 + q * 4) * HWSZ;
        o0[db]            = v.x; o0[db + HWSZ]     = v.y;
        o0[db + 2 * HWSZ] = v.z; o0[db + 3 * HWSZ] = v.w;
        o1[db]            = v.x; o1[db + HWSZ]     = v.y;
        o1[db + 2 * HWSZ] = v.z; o1[db + 3 * HWSZ] = v.w;
    }
}

extern "C" void kernel_launch(void* const* d_in, const int* in_sizes, int n_in,
                              void* d_out, int out_size, void* d_ws, size_t ws_size,
                              hipStream_t stream) {
    const float* z  = (const float*)d_in[0];   // [32,64,64,64] fp32
    const float* cb = (const float*)d_in[1];   // [512,64] fp32
    float* out = (float*)d_out;                // 2 * 8388608 fp32
    vq_np_argmin_pinned<<<NPOS / POSB, 256, 0, stream>>>(z, cb, out);
}

// Round 6
// 175.105 us; speedup vs baseline: 1.5477x; 1.3746x over previous
//
#include <hip/hip_runtime.h>

// VQ-VAE codebook quantization — MFMA-screened, np-bit-exact.
// Screen: split-bf16 (xh+xl)(ch+cl) via mfma_f32_16x16x32_bf16, 3 terms.
// Sound window W flags possible np-argmin ambiguity (~1% of positions);
// flagged positions re-scanned with the R2-verified exact np fp32 pipeline
// (pairwise sumsq, sequential FMA dot, fl(fl(cb+xs)-2dot), first-min).

typedef short bf16x8 __attribute__((ext_vector_type(8)));
typedef float f32x4  __attribute__((ext_vector_type(4)));

#define KCODES 512
#define DDIM 64
#define HWSZ 4096
#define NPOS 131072
#define POSB 128             // positions per block
#define NBLK (NPOS / POSB)   // 1024
#define OUT2_OFF 8388608
#define S_X 129              // x_lds pos-stride in floats (bank-spread)

__device__ __forceinline__ unsigned short f2bf_rne(float f) {
    unsigned u = __builtin_bit_cast(unsigned, f);
    unsigned r = u + 0x7FFFu + ((u >> 16) & 1u);
    return (unsigned short)(r >> 16);
}
__device__ __forceinline__ float bf2f(unsigned short h) {
    unsigned u = ((unsigned)h) << 16;
    return __builtin_bit_cast(float, u);
}

// numpy pairwise_sum (n=64 branch) of rounded squares, fp32, no fma.
__device__ __forceinline__ float np_sumsq64(const float* __restrict__ a) {
#pragma clang fp contract(off)
    float r0 = a[0]*a[0], r1 = a[1]*a[1], r2 = a[2]*a[2], r3 = a[3]*a[3];
    float r4 = a[4]*a[4], r5 = a[5]*a[5], r6 = a[6]*a[6], r7 = a[7]*a[7];
#pragma unroll
    for (int i = 8; i < 64; i += 8) {
        r0 += a[i+0]*a[i+0]; r1 += a[i+1]*a[i+1];
        r2 += a[i+2]*a[i+2]; r3 += a[i+3]*a[i+3];
        r4 += a[i+4]*a[i+4]; r5 += a[i+5]*a[i+5];
        r6 += a[i+6]*a[i+6]; r7 += a[i+7]*a[i+7];
    }
    return ((r0+r1)+(r2+r3)) + ((r4+r5)+(r6+r7));
}

// Prep: B-fragments (split bf16) in exact 16x16x32 B-operand layout + np cbsqr.
// ws layout: [0,128KB) bf16 frags [tile32][chunk2][split2][lane64][j8];
//            [128KB,130KB) fp32 cbsqr[512].
__global__ __launch_bounds__(256) void vq_prep(
    const float* __restrict__ cb, unsigned short* __restrict__ wsb,
    float* __restrict__ wscb)
{
    if (blockIdx.x < 128) {
        int u = blockIdx.x * 256 + threadIdx.x;   // u = k*64 + d
        int k = u >> 6, d = u & 63;
        float c = cb[u];
        unsigned short ch = f2bf_rne(c);
        float clf = c - bf2f(ch);                  // exact
        unsigned short cl = f2bf_rne(clf);
        int tile = k >> 4, n = k & 15;
        int chunk = d >> 5, quad = (d >> 3) & 3, j = d & 7;
        int lane = quad * 16 + n;                  // B: lane holds B[k=q*8+j][n]
        size_t base = ((((size_t)tile*2 + chunk)*2 + 0)*64 + lane)*8 + j;
        wsb[base]       = (unsigned short)ch;
        wsb[base + 512] = (unsigned short)cl;      // split stride = 64*8
    } else {
        int k = (blockIdx.x - 128) * 256 + threadIdx.x;
        if (k < KCODES) wscb[k] = np_sumsq64(cb + k * DDIM);
    }
}

__global__ __launch_bounds__(256, 4) void vq_main(
    const float* __restrict__ z, const float* __restrict__ cb,
    const unsigned short* __restrict__ wsb, const float* __restrict__ wscb,
    float* __restrict__ out)
{
#pragma clang fp contract(off)
    __shared__ float s_regA[64 * S_X];   // x_lds (33024 B), reused as B-stage (32768 B)
    __shared__ float s_cbsqr[KCODES];
    __shared__ float s_xsqr[POSB];
    __shared__ float s_part[2 * POSB];
    __shared__ int   s_idx[POSB];
    __shared__ int   s_flist[POSB];
    __shared__ int   s_cnt;

    const int tid = threadIdx.x;
    const int wv = tid >> 6, ln = tid & 63;
    const int m = ln & 15, q = ln >> 4;
    const int n0 = blockIdx.x * POSB;
    const long gbase = (long)(n0 >> 12) * (DDIM * HWSZ) + (n0 & 4095);

    if (tid == 0) s_cnt = 0;
    s_cbsqr[tid] = wscb[tid];
    s_cbsqr[tid + 256] = wscb[tid + 256];

    // ---- phase 1: z -> x_lds, d-major [d][pos], coalesced ----
#pragma unroll
    for (int i = 0; i < 32; ++i) {
        int d = wv * 16 + (i & 15), ph = i >> 4;
        s_regA[d * S_X + ph * 64 + ln] = z[gbase + (long)d * HWSZ + ph * 64 + ln];
    }
    __syncthreads();

    // ---- phase 2a: np xsqr partials (thread -> (p, h)) ----
    {
        int p = tid & 127, h = tid >> 7;
        float r0 = 0.f, r1 = 0.f, r2 = 0.f, r3 = 0.f;
#pragma unroll
        for (int i = 0; i < 8; ++i) {
            float a0 = s_regA[(8*i + 4*h + 0) * S_X + p];
            float a1 = s_regA[(8*i + 4*h + 1) * S_X + p];
            float a2 = s_regA[(8*i + 4*h + 2) * S_X + p];
            float a3 = s_regA[(8*i + 4*h + 3) * S_X + p];
            r0 += a0*a0; r1 += a1*a1; r2 += a2*a2; r3 += a3*a3;
        }
        s_part[h * POSB + p] = (r0 + r1) + (r2 + r3);
    }

    // ---- phase 2b: A-fragments (per wave: 2 row-tiles x 2 K-chunks, split) ----
    bf16x8 Ah[4], Al[4];
#pragma unroll
    for (int rt = 0; rt < 2; ++rt)
#pragma unroll
        for (int c = 0; c < 2; ++c) {
            int pos = wv * 32 + rt * 16 + m;
            bf16x8 ah, al;
#pragma unroll
            for (int j = 0; j < 8; ++j) {
                float xv = s_regA[(c*32 + q*8 + j) * S_X + pos];
                unsigned short hh = f2bf_rne(xv);
                float lo = xv - bf2f(hh);          // exact
                ah[j] = (short)hh;
                al[j] = (short)f2bf_rne(lo);
            }
            Ah[rt*2 + c] = ah; Al[rt*2 + c] = al;
        }
    __syncthreads();
    if (tid < POSB) s_xsqr[tid] = s_part[tid] + s_part[POSB + tid]; // np (A+B)

    // ---- phase 3: screen all 512 codes, B staged in 4 groups of 8 tiles ----
    float m1[8], m2[8]; int t1[8];
#pragma unroll
    for (int i = 0; i < 8; ++i) { m1[i] = 3.4e38f; m2[i] = 3.4e38f; t1[i] = 0; }

    for (int g = 0; g < 4; ++g) {
        __syncthreads();   // prior reads of s_regA done (g=0: A-frags/xsqr)
        const float4* src = (const float4*)wsb + g * 2048;
        float4* dst = (float4*)s_regA;
#pragma unroll
        for (int i = 0; i < 8; ++i) dst[i * 256 + tid] = src[i * 256 + tid];
        __syncthreads();

        const unsigned short* sb = (const unsigned short*)s_regA;
        for (int ti = 0; ti < 8; ++ti) {
            int t = g * 8 + ti;
            bf16x8 Bh0 = *(const bf16x8*)(sb + ((ti*2+0)*2+0)*512 + ln*8);
            bf16x8 Bl0 = *(const bf16x8*)(sb + ((ti*2+0)*2+1)*512 + ln*8);
            bf16x8 Bh1 = *(const bf16x8*)(sb + ((ti*2+1)*2+0)*512 + ln*8);
            bf16x8 Bl1 = *(const bf16x8*)(sb + ((ti*2+1)*2+1)*512 + ln*8);
            float cbv = s_cbsqr[t * 16 + m];
#pragma unroll
            for (int rt = 0; rt < 2; ++rt) {
                f32x4 acc = {0.f, 0.f, 0.f, 0.f};
                acc = __builtin_amdgcn_mfma_f32_16x16x32_bf16(Al[rt*2+0], Bh0, acc, 0,0,0);
                acc = __builtin_amdgcn_mfma_f32_16x16x32_bf16(Ah[rt*2+0], Bl0, acc, 0,0,0);
                acc = __builtin_amdgcn_mfma_f32_16x16x32_bf16(Ah[rt*2+0], Bh0, acc, 0,0,0);
                acc = __builtin_amdgcn_mfma_f32_16x16x32_bf16(Al[rt*2+1], Bh1, acc, 0,0,0);
                acc = __builtin_amdgcn_mfma_f32_16x16x32_bf16(Ah[rt*2+1], Bl1, acc, 0,0,0);
                acc = __builtin_amdgcn_mfma_f32_16x16x32_bf16(Ah[rt*2+1], Bh1, acc, 0,0,0);
#pragma unroll
                for (int r = 0; r < 4; ++r) {
                    float sc = fmaf(-2.f, acc[r], cbv);
                    int cell = rt * 4 + r;
                    bool lt = sc < m1[cell];
                    m2[cell] = fminf(m2[cell], lt ? m1[cell] : sc);
                    if (lt) { m1[cell] = sc; t1[cell] = t; }
                }
            }
        }
    }

    // ---- phase 4: per-position reduce over 16 lanes; flag ambiguity ----
#pragma unroll
    for (int cell = 0; cell < 8; ++cell) {
        int rt = cell >> 2, r = cell & 3;
        float v1 = m1[cell], v2 = m2[cell];
        int i1 = t1[cell] * 16 + m;
#pragma unroll
        for (int s = 1; s < 16; s <<= 1) {
            float o1 = __shfl_xor(v1, s);
            float o2 = __shfl_xor(v2, s);
            int   oi = __shfl_xor(i1, s);
            bool take = (o1 < v1) || (o1 == v1 && oi < i1);
            float lose = take ? v1 : o1;
            if (take) { v1 = o1; i1 = oi; }
            v2 = fminf(fminf(v2, o2), lose);
        }
        if (m == 0) {
            int pos = wv * 32 + rt * 16 + q * 4 + r;
            float xs = s_xsqr[pos];
            float sx = 8.0f * sqrtf(xs) * 1.01f;       // >= sum |x_d|
            float amax = 0.00196f * sx + 0.01f;        // >= sum|x c| + margin
            float eps = 1.5f * (3.0f * 1.52587890625e-5f * 0.00196f * sx
                                + 500.f * 5.96e-8f * amax);
            float delta = 2.4e-7f * (xs + 1.0f) + 64.f * 1.2e-7f * amax;
            float W = 2.f * eps + 2.f * delta + 1e-9f;
            int flag = (v2 - v1 <= W) ? (1 << 30) : 0;
            s_idx[pos] = i1 | flag;
        }
    }
    __syncthreads();
    if (tid < POSB) {
        if (s_idx[tid] & (1 << 30)) {
            int slot = atomicAdd(&s_cnt, 1);
            s_flist[slot] = tid;
        }
    }
    __syncthreads();

    // ---- phase 5: np-exact refine of flagged positions ----
    const int cnt = s_cnt;
    for (int i = wv; i < cnt; i += 4) {
        int p = __builtin_amdgcn_readfirstlane(s_flist[i]);
        float xv = z[gbase + (long)ln * HWSZ + p];   // lane ln holds x[d=ln]
        float xs = s_xsqr[p];
        float dot[8];
#pragma unroll
        for (int j = 0; j < 8; ++j) dot[j] = 0.f;
        const float* crow = cb + (ln * 8) * DDIM;    // lane's 8 codes
        for (int dc = 0; dc < 16; ++dc) {
            float x0 = __shfl(xv, dc*4 + 0);
            float x1 = __shfl(xv, dc*4 + 1);
            float x2 = __shfl(xv, dc*4 + 2);
            float x3 = __shfl(xv, dc*4 + 3);
#pragma unroll
            for (int j = 0; j < 8; ++j) {
                float4 cv = *(const float4*)(crow + j * DDIM + dc * 4);
                dot[j] = fmaf(x0, cv.x, dot[j]);
                dot[j] = fmaf(x1, cv.y, dot[j]);
                dot[j] = fmaf(x2, cv.z, dot[j]);
                dot[j] = fmaf(x3, cv.w, dot[j]);
            }
        }
        float bv = 3.4e38f; int bi = 0;
#pragma unroll
        for (int j = 0; j < 8; ++j) {
            int k = ln * 8 + j;
            float tt = s_cbsqr[k] + xs;
            float e = fmaf(-2.f, dot[j], tt);
            if (e < bv) { bv = e; bi = k; }
        }
#pragma unroll
        for (int s = 1; s < 64; s <<= 1) {
            float ov = __shfl_xor(bv, s); int oi = __shfl_xor(bi, s);
            if (ov < bv || (ov == bv && oi < bi)) { bv = ov; bi = oi; }
        }
        if (ln == 0) s_idx[p] = bi;
    }
    __syncthreads();

    // ---- phase 6: scatter selected codes to both outputs (NCHW) ----
    {
        int p = tid & 127, hf = tid >> 7;
        int idx = s_idx[p] & 0x3FFFFFFF;
        const float4* crow4 = (const float4*)(cb + idx * DDIM + hf * 32);
        float* o0 = out + gbase + p;
        float* o1 = o0 + OUT2_OFF;
#pragma unroll
        for (int qq = 0; qq < 8; ++qq) {
            float4 v = crow4[qq];
            long db = (long)(hf * 32 + qq * 4) * HWSZ;
            o0[db]          = v.x; o0[db + HWSZ]   = v.y;
            o0[db + 2*HWSZ] = v.z; o0[db + 3*HWSZ] = v.w;
            o1[db]          = v.x; o1[db + HWSZ]   = v.y;
            o1[db + 2*HWSZ] = v.z; o1[db + 3*HWSZ] = v.w;
        }
    }
}

extern "C" void kernel_launch(void* const* d_in, const int* in_sizes, int n_in,
                              void* d_out, int out_size, void* d_ws, size_t ws_size,
                              hipStream_t stream) {
    const float* z  = (const float*)d_in[0];   // [32,64,64,64] fp32
    const float* cb = (const float*)d_in[1];   // [512,64] fp32
    float* out = (float*)d_out;                // 2 * 8388608 fp32
    unsigned short* wsb = (unsigned short*)d_ws;            // 128 KB frags
    float* wscb = (float*)((char*)d_ws + 131072);           // 2 KB cbsqr
    vq_prep<<<130, 256, 0, stream>>>(cb, wsb, wscb);
    vq_main<<<NBLK, 256, 0, stream>>>(z, cb, wsb, wscb, out);
}